// Round 23
// baseline (173.745 us; speedup 1.0000x reference)
//
#include <hip/hip_runtime.h>
#include <hip/hip_bf16.h>
#include <stdint.h>

// B=4, T=2048, C=1024, H=16, hd=64
// qkv bf16 [8192][3072] (cols: 0..1023=Q, 1024..2047=K, 2048..3071=V; within: h*64+d)
//   NOTE: Wq/bq are pre-scaled by log2(e)/32, so softmax = exp2(S).
// vT bf16 [(bb*16+h)*64+d][2048]: sigma-permuted per 64-token tile.
// r23 = r22 with QKV GEMM -> gemm19: A-fragments read DIRECTLY from global (L2-hot,
//   panel reused by 12 n-blocks) — deletes A's LDS writes+reads (LDS was the binding
//   resource at 2540 vs MFMA 1866 cyc/CU-K-tile). LDS = B-dbuf only (32KB, 3 blocks/CU).
// proj: gemm9. attn: r22 (MFMA row-sums, tri-buffer).

typedef unsigned short u16;
typedef __attribute__((ext_vector_type(4))) float f32x4;
typedef __attribute__((ext_vector_type(8))) __bf16 bf16x8;
typedef __attribute__((ext_vector_type(2))) __bf16 bf16x2;

#define DEV static __device__ __forceinline__

DEV u16 f2bf(float f) {  // RNE float->bf16 (finite inputs only)
  uint32_t u = __builtin_bit_cast(uint32_t, f);
  return (u16)((u + 0x7FFFu + ((u >> 16) & 1u)) >> 16);
}

DEV uint pack2(float a, float b) {  // v_cvt_pk_bf16_f32 via vector of casts
  bf16x2 v;
  v.x = (__bf16)a;
  v.y = (__bf16)b;
  return __builtin_bit_cast(uint, v);
}

#if __has_builtin(__builtin_amdgcn_exp2f)
DEV float fexp2(float x) { return __builtin_amdgcn_exp2f(x); }
#else
DEV float fexp2(float x) { return __expf(x * 0.69314718056f); }
#endif

DEV void gload_lds16(const void* g, void* lds) {  // 16B/lane global->LDS direct
  auto gp = reinterpret_cast<const __attribute__((address_space(1))) uint32_t*>(
      reinterpret_cast<uintptr_t>(g));
  auto lp = reinterpret_cast<__attribute__((address_space(3))) uint32_t*>(
      static_cast<uint32_t>(reinterpret_cast<uintptr_t>(lds)));
  __builtin_amdgcn_global_load_lds(gp, lp, 16, 0, 0);
}

DEV f32x4 mfma16(bf16x8 a, bf16x8 b, f32x4 c) {
  return __builtin_amdgcn_mfma_f32_16x16x32_bf16(a, b, c, 0, 0, 0);
}

DEV void bar() {  // raw s_barrier + compiler memory fence
  asm volatile("" ::: "memory");
  __builtin_amdgcn_s_barrier();
  asm volatile("" ::: "memory");
}

#define LD8(p) (*reinterpret_cast<const bf16x8*>(p))
#define LDU4(p) (*reinterpret_cast<const uint4*>(p))

// ---------------- conversion kernels ----------------

__global__ void cvt_x_kernel(const float* __restrict__ x, u16* __restrict__ xb, int n8) {
  int i = blockIdx.x * blockDim.x + threadIdx.x;
  int stride = gridDim.x * blockDim.x;
  for (; i < n8; i += stride) {
    const float4* xp = reinterpret_cast<const float4*>(x) + 2 * (size_t)i;
    float4 a = xp[0], b = xp[1];
    uint4 o;
    o.x = pack2(a.x, a.y);
    o.y = pack2(a.z, a.w);
    o.z = pack2(b.x, b.y);
    o.w = pack2(b.z, b.w);
    reinterpret_cast<uint4*>(xb)[i] = o;
  }
}

// Wq/Wk/Wv [16][1024][64] -> wt[n=which*1024+h*64+d][c] (bf16), biasq[n].
__global__ void cvt_wqkv_kernel(const float* __restrict__ Wq, const float* __restrict__ Wk,
                                const float* __restrict__ Wv, const float* __restrict__ bq,
                                const float* __restrict__ bk, const float* __restrict__ bv,
                                u16* __restrict__ wt, float* __restrict__ biasq) {
  __shared__ u16 tle[64 * 72];
  const int tid = threadIdx.x;
  const int ct = blockIdx.x;     // c-tile 0..15
  const int h = blockIdx.y;      // 0..15
  const int which = blockIdx.z;  // 0..2
  const float* W = (which == 0) ? Wq : (which == 1) ? Wk : Wv;
  const float* Bb = (which == 0) ? bq : (which == 1) ? bk : bv;
  const float scl = (which == 0) ? 0.045084220027780106f : 1.0f;  // log2(e)/32
#pragma unroll
  for (int i = 0; i < 4; ++i) {
    int idx = i * 256 + tid;
    int c_l = idx >> 4, d4 = (idx & 15) * 4;
    float4 v = *reinterpret_cast<const float4*>(&W[((size_t)(h * 1024 + ct * 64 + c_l)) * 64 + d4]);
    tle[(d4 + 0) * 72 + c_l] = f2bf(v.x * scl);
    tle[(d4 + 1) * 72 + c_l] = f2bf(v.y * scl);
    tle[(d4 + 2) * 72 + c_l] = f2bf(v.z * scl);
    tle[(d4 + 3) * 72 + c_l] = f2bf(v.w * scl);
  }
  __syncthreads();
#pragma unroll
  for (int i = 0; i < 2; ++i) {
    int idx = i * 256 + tid;
    int d_o = idx >> 3, c8 = (idx & 7) * 8;
    uint4 v = LDU4(&tle[d_o * 72 + c8]);
    *reinterpret_cast<uint4*>(&wt[(size_t)(which * 1024 + h * 64 + d_o) * 1024 + ct * 64 + c8]) = v;
  }
  if (ct == 0 && tid < 64) biasq[which * 1024 + h * 64 + tid] = Bb[h * 64 + tid] * scl;
}

// Wp [1024][1024] -> wpt[n][c] = Wp[c][n]
__global__ void cvt_wp_kernel(const float* __restrict__ Wp, u16* __restrict__ wpt) {
  __shared__ u16 tle[64 * 72];
  const int tid = threadIdx.x;
  const int ct = blockIdx.x;
  const int nt = blockIdx.y;
#pragma unroll
  for (int i = 0; i < 4; ++i) {
    int idx = i * 256 + tid;
    int c_l = idx >> 4, n4 = (idx & 15) * 4;
    float4 v = *reinterpret_cast<const float4*>(&Wp[(size_t)(ct * 64 + c_l) * 1024 + nt * 64 + n4]);
    tle[(n4 + 0) * 72 + c_l] = f2bf(v.x);
    tle[(n4 + 1) * 72 + c_l] = f2bf(v.y);
    tle[(n4 + 2) * 72 + c_l] = f2bf(v.z);
    tle[(n4 + 3) * 72 + c_l] = f2bf(v.w);
  }
  __syncthreads();
#pragma unroll
  for (int i = 0; i < 2; ++i) {
    int idx = i * 256 + tid;
    int n_o = idx >> 3, c8 = (idx & 7) * 8;
    uint4 v = LDU4(&tle[n_o * 72 + c8]);
    *reinterpret_cast<uint4*>(&wpt[(size_t)(nt * 64 + n_o) * 1024 + ct * 64 + c8]) = v;
  }
}

// qkv V-part -> vT[(bb*16+h)*64+d][2048], sigma-permuted per 64-token tile.
__global__ __launch_bounds__(256)
void transpose_v_kernel(const u16* __restrict__ qkv, u16* __restrict__ vT) {
  __shared__ alignas(16) u16 tle[64 * 72];
  const int tid = threadIdx.x;
  const int tt = blockIdx.x;  // token tile 0..31
  const int h = blockIdx.y;   // 0..15
  const int bb = blockIdx.z;  // 0..3
  const size_t rbase = ((size_t)bb * 2048 + tt * 64) * 3072 + 2048 + h * 64;
#pragma unroll
  for (int i = 0; i < 2; ++i) {
    int idx = i * 256 + tid;  // 0..511
    int s = idx >> 3, c8 = (idx & 7) * 8;
    *reinterpret_cast<uint4*>(&tle[s * 72 + c8]) = LDU4(&qkv[rbase + (size_t)s * 3072 + c8]);
  }
  __syncthreads();
#pragma unroll
  for (int i = 0; i < 2; ++i) {
    int idx = i * 256 + tid;
    int d = idx >> 3, cb = idx & 7;
    uint4 o;
    o.x = (uint)tle[(2 * cb + 0) * 72 + d] | ((uint)tle[(16 + 2 * cb + 0) * 72 + d] << 16);
    o.y = (uint)tle[(32 + 2 * cb + 0) * 72 + d] | ((uint)tle[(48 + 2 * cb + 0) * 72 + d] << 16);
    o.z = (uint)tle[(2 * cb + 1) * 72 + d] | ((uint)tle[(16 + 2 * cb + 1) * 72 + d] << 16);
    o.w = (uint)tle[(32 + 2 * cb + 1) * 72 + d] | ((uint)tle[(48 + 2 * cb + 1) * 72 + d] << 16);
    *reinterpret_cast<uint4*>(
        &vT[((size_t)(bb * 16 + h) * 64 + d) * 2048 + tt * 64 + cb * 8]) = o;
  }
}

// ---------------- gemm19: 128x256, BK=32, A direct-from-global, B-dbuf LDS ------------
// 4 waves x (64x128 wave tile, acc[4][8]); A fragments loaded straight from global at
// iter top (L2-hot panel; latency hidden by bF LDS reads + 12 waves/CU TLP); LDS holds
// only B (2x16KB). B staging swizzle/vmcnt(0)/barrier identical to gemm17.

template <bool OUT_F32>
__global__ __launch_bounds__(256, 3)
void gemm19_kernel(const u16* __restrict__ A, const u16* __restrict__ Bt,
                   const float* __restrict__ bias, void* __restrict__ Cout,
                   int M, int N, int K, int nbn) {
  __shared__ alignas(16) u16 LB[2 * 8192];  // 2 x (256x32) = 32 KB

  const int tid = threadIdx.x;   // 0..255
  const int lane = tid & 63;
  const int wave = tid >> 6;     // 0..3
  const int wm = wave >> 1;      // 0..1 -> rows wm*64
  const int wn = wave & 1;       // 0..1 -> cols wn*128
  const int fr = lane & 15;
  const int kg = lane >> 4;
  const int kg8 = kg * 8;
  const int r4 = kg * 4;

  const int nwg = gridDim.x;
  const int swz = (blockIdx.x & 7) * (nwg >> 3) + (blockIdx.x >> 3);
  const int m0 = (swz / nbn) * 128;
  const int n0 = (swz % nbn) * 256;
  const int NT = K >> 5;

  // per-lane A row bases (4 rows per wave's m-fragments)
  const u16* aR0 = A + (size_t)(m0 + wm * 64 + 0 * 16 + fr) * K + kg8;
  const u16* aR1 = A + (size_t)(m0 + wm * 64 + 1 * 16 + fr) * K + kg8;
  const u16* aR2 = A + (size_t)(m0 + wm * 64 + 2 * 16 + fr) * K + kg8;
  const u16* aR3 = A + (size_t)(m0 + wm * 64 + 3 * 16 + fr) * K + kg8;

  auto stageB = [&](int kt, u16* d) {
#pragma unroll
    for (int i = 0; i < 4; ++i) {
      const int c = i * 256 + tid;
      const int row = c >> 2;
      const int ss = (((c & 3) ^ ((row >> 1) & 3)) << 3);
      gload_lds16(Bt + (size_t)(n0 + row) * K + (size_t)kt * 32 + ss, d + c * 8);
    }
  };

  f32x4 acc[4][8] = {};

  stageB(0, LB);
  asm volatile("s_waitcnt vmcnt(0)" ::: "memory");
  bar();

  for (int kt = 0; kt < NT; ++kt) {
    const bool st1 = (kt + 1 < NT);
    u16* lb = LB + (kt & 1) * 8192;

    if (st1) stageB(kt + 1, LB + ((kt + 1) & 1) * 8192);

    // A fragments direct from global (L2-hot; issued before bF reads so latency hides)
    const size_t ko = (size_t)kt * 32;
    bf16x8 aF0 = LD8(aR0 + ko);
    bf16x8 aF1 = LD8(aR1 + ko);
    bf16x8 aF2 = LD8(aR2 + ko);
    bf16x8 aF3 = LD8(aR3 + ko);

    __builtin_amdgcn_s_setprio(1);
#pragma unroll
    for (int n = 0; n < 8; ++n) {
      const int R = wn * 128 + n * 16 + fr;
      bf16x8 bF = LD8(&lb[R * 32 + ((kg ^ ((R >> 1) & 3)) << 3)]);
      acc[0][n] = mfma16(aF0, bF, acc[0][n]);
      acc[1][n] = mfma16(aF1, bF, acc[1][n]);
      acc[2][n] = mfma16(aF2, bF, acc[2][n]);
      acc[3][n] = mfma16(aF3, bF, acc[3][n]);
    }
    __builtin_amdgcn_s_setprio(0);

    if (st1) {
      asm volatile("s_waitcnt vmcnt(0)" ::: "memory");
      bar();
    }
  }

#pragma unroll
  for (int m = 0; m < 4; ++m) {
    const int row = m0 + wm * 64 + m * 16 + r4;
#pragma unroll
    for (int n = 0; n < 8; ++n) {
      const int col = n0 + wn * 128 + n * 16 + fr;
      const float bv = bias[col];
#pragma unroll
      for (int r = 0; r < 4; ++r) {
        float v = acc[m][n][r] + bv;
        size_t off = (size_t)(row + r) * N + col;
        if constexpr (OUT_F32) reinterpret_cast<float*>(Cout)[off] = v;
        else                   reinterpret_cast<u16*>(Cout)[off] = f2bf(v);
      }
    }
  }
}

// ---------------- gemm9: 128x256, BK=64, A-dbuf + B-tribuf (counted vmcnt) — for proj ----------------

template <bool OUT_F32>
__global__ __launch_bounds__(512, 2)
void gemm9_kernel(const u16* __restrict__ A, const u16* __restrict__ Bt,
                  const float* __restrict__ bias, void* __restrict__ Cout,
                  int M, int N, int K, int nbn) {
  __shared__ alignas(16) u16 LA[2 * 8192];
  __shared__ alignas(16) u16 LB[3 * 16384];

  const int tid = threadIdx.x;
  const int lane = tid & 63;
  const int wave = tid >> 6;
  const int wm = wave >> 2;
  const int wn = wave & 3;
  const int fr = lane & 15;
  const int kg = lane >> 4;
  const int f7 = fr & 7;
  const int r4 = kg * 4;

  const int nwg = gridDim.x;
  const int swz = (blockIdx.x & 7) * (nwg >> 3) + (blockIdx.x >> 3);
  const int m0 = (swz / nbn) * 128;
  const int n0 = (swz % nbn) * 256;
  const int NT = K >> 6;

  const int srow = tid >> 3;
  const int sgcol = ((tid & 7) ^ (srow & 7)) << 3;
  const size_t aOff = (size_t)(m0 + srow) * K + sgcol;
  const size_t bOff = (size_t)(n0 + srow) * K + sgcol;
  const int ldst = tid * 8;

  auto stageA = [&](int kt, u16* labuf) {
    gload_lds16(A + aOff + (size_t)kt * 64, labuf + ldst);
    gload_lds16(A + aOff + (size_t)64 * K + (size_t)kt * 64, labuf + 4096 + ldst);
  };
  auto stageB = [&](int kt, u16* lbbuf) {
    gload_lds16(Bt + bOff + (size_t)kt * 64, lbbuf + ldst);
    gload_lds16(Bt + bOff + (size_t)64 * K + (size_t)kt * 64, lbbuf + 4096 + ldst);
    gload_lds16(Bt + bOff + (size_t)128 * K + (size_t)kt * 64, lbbuf + 8192 + ldst);
    gload_lds16(Bt + bOff + (size_t)192 * K + (size_t)kt * 64, lbbuf + 12288 + ldst);
  };

  f32x4 acc[4][4] = {};

  stageA(0, LA);
  stageB(0, LB);
  if (NT > 1) {
    stageB(1, LB + 16384);
    asm volatile("s_waitcnt vmcnt(4)" ::: "memory");
  } else {
    asm volatile("s_waitcnt vmcnt(0)" ::: "memory");
  }
  bar();

  for (int kt = 0; kt < NT; ++kt) {
    const bool st1 = (kt + 1 < NT);
    const bool st2 = (kt + 2 < NT);
    u16* laCur = LA + (kt & 1) * 8192;
    u16* lbCur = LB + (kt % 3) * 16384;

    if (st1) stageA(kt + 1, LA + ((kt + 1) & 1) * 8192);
    if (st2) stageB(kt + 2, LB + ((kt + 2) % 3) * 16384);

    bf16x8 aF[4][2], bF[4][2];
#pragma unroll
    for (int m = 0; m < 4; ++m)
#pragma unroll
      for (int ks = 0; ks < 2; ++ks)
        aF[m][ks] = LD8(&laCur[wm * 4096 + (m * 16 + fr) * 64 + (((ks * 4 + kg) ^ f7) << 3)]);
#pragma unroll
    for (int n = 0; n < 4; ++n)
#pragma unroll
      for (int ks = 0; ks < 2; ++ks)
        bF[n][ks] = LD8(&lbCur[wn * 4096 + (n * 16 + fr) * 64 + (((ks * 4 + kg) ^ f7) << 3)]);

    __builtin_amdgcn_s_setprio(1);
#pragma unroll
    for (int ks = 0; ks < 2; ++ks)
#pragma unroll
      for (int m = 0; m < 4; ++m)
#pragma unroll
        for (int n = 0; n < 4; ++n)
          acc[m][n] = mfma16(aF[m][ks], bF[n][ks], acc[m][n]);
    __builtin_amdgcn_s_setprio(0);

    if (st1) {
      if (st2) asm volatile("s_waitcnt vmcnt(4)" ::: "memory");
      else     asm volatile("s_waitcnt vmcnt(0)" ::: "memory");
      bar();
    }
  }

#pragma unroll
  for (int m = 0; m < 4; ++m) {
    const int row = m0 + wm * 64 + m * 16 + r4;
#pragma unroll
    for (int n = 0; n < 4; ++n) {
      const int col = n0 + wn * 64 + n * 16 + fr;
      const float bv = bias[col];
#pragma unroll
      for (int r = 0; r < 4; ++r) {
        float v = acc[m][n][r] + bv;
        size_t off = (size_t)(row + r) * N + col;
        if constexpr (OUT_F32) reinterpret_cast<float*>(Cout)[off] = v;
        else                   reinterpret_cast<u16*>(Cout)[off] = f2bf(v);
      }
    }
  }
}

// ---------------- causal flash attention: 4 waves x 32 q-rows, MFMA row-sums (r22) ----------

__global__ __launch_bounds__(256, 2)
void attn_kernel(const u16* __restrict__ qkv, const u16* __restrict__ vT,
                 u16* __restrict__ obuf) {
  __shared__ alignas(16) u16 Ks[3][64 * 64];
  __shared__ alignas(16) u16 Vs[3][64 * 64];
  __shared__ alignas(16) u16 Ps[4][32 * 72];

  const int tid = threadIdx.x;
  const int lane = tid & 63;
  const int wave = tid >> 6;  // 0..3

  const int gid = blockIdx.x;
  const int xcd = gid & 7;
  const int j = gid >> 3;            // 0..63
  const int g = xcd * 8 + (j >> 3);  // 0..63 (b,h) group
  const int pair = j & 7;            // 0..7
  const int bb = g >> 4;
  const int h = g & 15;

  const size_t baseQ = (size_t)bb * 2048 * 3072 + h * 64;
  const size_t baseK = baseQ + 1024;
  const size_t baseVt = (size_t)(bb * 16 + h) * 64 * 2048;

  const int fr = lane & 15;
  const int kg = lane >> 4;
  const int kg8 = kg * 8;
  const int r4 = kg * 4;
  const int f7 = fr & 7;
  const int ko0 = (kg ^ f7) * 8;        // ks=0 swizzled u16 offset
  const int ko1 = ((4 + kg) ^ f7) * 8;  // ks=1
  u16* __restrict__ Pw = &Ps[wave][0];

  const __bf16 one1 = (__bf16)1.0f;
  const bf16x8 one8 = {one1, one1, one1, one1, one1, one1, one1, one1};

  auto stageKV = [&](int t, int bi) {  // 4 gloads/thread (full 64x64 K and V tiles)
    const u16* kS = qkv + baseK + (size_t)t * 64 * 3072;
    const u16* vS = vT + baseVt + (size_t)t * 64;
#pragma unroll
    for (int i = 0; i < 2; ++i) {
      const int c = i * 256 + tid;
      const int rr = c >> 3;
      const int ss = ((c & 7) ^ (rr & 7)) * 8;
      gload_lds16(kS + (size_t)rr * 3072 + ss, &Ks[bi][c * 8]);
      gload_lds16(vS + (size_t)rr * 2048 + ss, &Vs[bi][c * 8]);
    }
  };

  for (int half = 0; half < 2; ++half) {
    const int qt = half ? (15 - pair) : pair;
    const int q0 = qt * 128;
    const int nt = 2 * qt + 2;              // >= 2 always
    const int qw = wave * 32;
    const int myNt = nt - 1 + (wave >> 1);  // waves 0,1 skip final tile (fully masked)
    const int qdb = qw & 63;                // diag threshold base (0 or 32)

    const u16* qr = &qkv[baseQ + (size_t)(q0 + qw + fr) * 3072 + kg8];
    bf16x8 aq00 = LD8(qr), aq01 = LD8(qr + 32);
    bf16x8 aq10 = LD8(qr + 16 * 3072), aq11 = LD8(qr + 16 * 3072 + 32);

    f32x4 lsA = {}, lsB = {};
    f32x4 oA0 = {}, oA1 = {}, oA2 = {}, oA3 = {};
    f32x4 oB0 = {}, oB1 = {}, oB2 = {}, oB3 = {};

    // prologue: stage tiles 0,1; drain only tile 0 (counted)
    stageKV(0, 0);
    stageKV(1, 1);
    asm volatile("s_waitcnt vmcnt(4)" ::: "memory");
    bar();

    for (int t = 0; t < nt; ++t) {
      const bool st2 = (t + 2 < nt);
      if (st2) stageKV(t + 2, (t + 2) % 3);

      if (t < myNt) {
        const u16* ks = &Ks[t % 3][0];
        const u16* vs = &Vs[t % 3][0];

        f32x4 sA0 = {}, sA1 = {}, sA2 = {}, sA3 = {};
        f32x4 sB0 = {}, sB1 = {}, sB2 = {}, sB3 = {};
        {
          bf16x8 b;
          __builtin_amdgcn_s_setprio(1);
          b = LD8(&ks[(fr) * 64 + ko0]);      sA0 = mfma16(aq00, b, sA0); sB0 = mfma16(aq10, b, sB0);
          b = LD8(&ks[(16 + fr) * 64 + ko0]); sA1 = mfma16(aq00, b, sA1); sB1 = mfma16(aq10, b, sB1);
          b = LD8(&ks[(32 + fr) * 64 + ko0]); sA2 = mfma16(aq00, b, sA2); sB2 = mfma16(aq10, b, sB2);
          b = LD8(&ks[(48 + fr) * 64 + ko0]); sA3 = mfma16(aq00, b, sA3); sB3 = mfma16(aq10, b, sB3);
          b = LD8(&ks[(fr) * 64 + ko1]);      sA0 = mfma16(aq01, b, sA0); sB0 = mfma16(aq11, b, sB0);
          b = LD8(&ks[(16 + fr) * 64 + ko1]); sA1 = mfma16(aq01, b, sA1); sB1 = mfma16(aq11, b, sB1);
          b = LD8(&ks[(32 + fr) * 64 + ko1]); sA2 = mfma16(aq01, b, sA2); sB2 = mfma16(aq11, b, sB2);
          b = LD8(&ks[(48 + fr) * 64 + ko1]); sA3 = mfma16(aq01, b, sA3); sB3 = mfma16(aq11, b, sB3);
          __builtin_amdgcn_s_setprio(0);
        }

        const bool diag = (t == myNt - 1);
#define SM_ROW_G(S0, S1, S2, S3, RB, r)                                        \
        {                                                                      \
          const int qd = qdb + RB + r4 + r;                                    \
          float p0 = fexp2(S0[r]);                                             \
          float p1 = fexp2(S1[r]);                                             \
          float p2 = fexp2(S2[r]);                                             \
          float p3 = fexp2(S3[r]);                                             \
          if (diag) {                                                          \
            if (fr > qd) p0 = 0.f;                                             \
            if (fr + 16 > qd) p1 = 0.f;                                        \
            if (fr + 32 > qd) p2 = 0.f;                                        \
            if (fr + 48 > qd) p3 = 0.f;                                        \
          }                                                                    \
          uint2 w;                                                             \
          w.x = pack2(p0, p1);                                                 \
          w.y = pack2(p2, p3);                                                 \
          *reinterpret_cast<uint2*>(&Pw[(RB + r4 + r) * 72 + fr * 4]) = w;     \
        }
        SM_ROW_G(sA0, sA1, sA2, sA3, 0, 0)
        SM_ROW_G(sA0, sA1, sA2, sA3, 0, 1)
        SM_ROW_G(sA0, sA1, sA2, sA3, 0, 2)
        SM_ROW_G(sA0, sA1, sA2, sA3, 0, 3)
        SM_ROW_G(sB0, sB1, sB2, sB3, 16, 0)
        SM_ROW_G(sB0, sB1, sB2, sB3, 16, 1)
        SM_ROW_G(sB0, sB1, sB2, sB3, 16, 2)
        SM_ROW_G(sB0, sB1, sB2, sB3, 16, 3)
#undef SM_ROW_G

        {
          bf16x8 pfA = LD8(&Pw[fr * 72 + kg8]);
          bf16x8 pfB = LD8(&Pw[(16 + fr) * 72 + kg8]);
          bf16x8 v;
          __builtin_amdgcn_s_setprio(1);
          lsA = mfma16(pfA, one8, lsA);       // row sums (all D cols equal)
          lsB = mfma16(pfB, one8, lsB);
          v = LD8(&vs[(fr) * 64 + ko0]);      oA0 = mfma16(pfA, v, oA0); oB0 = mfma16(pfB, v, oB0);
          v = LD8(&vs[(16 + fr) * 64 + ko0]); oA1 = mfma16(pfA, v, oA1); oB1 = mfma16(pfB, v, oB1);
          v = LD8(&vs[(32 + fr) * 64 + ko0]); oA2 = mfma16(pfA, v, oA2); oB2 = mfma16(pfB, v, oB2);
          v = LD8(&vs[(48 + fr) * 64 + ko0]); oA3 = mfma16(pfA, v, oA3); oB3 = mfma16(pfB, v, oB3);
          pfA = LD8(&Pw[fr * 72 + 32 + kg8]);
          pfB = LD8(&Pw[(16 + fr) * 72 + 32 + kg8]);
          lsA = mfma16(pfA, one8, lsA);
          lsB = mfma16(pfB, one8, lsB);
          v = LD8(&vs[(fr) * 64 + ko1]);      oA0 = mfma16(pfA, v, oA0); oB0 = mfma16(pfB, v, oB0);
          v = LD8(&vs[(16 + fr) * 64 + ko1]); oA1 = mfma16(pfA, v, oA1); oB1 = mfma16(pfB, v, oB1);
          v = LD8(&vs[(32 + fr) * 64 + ko1]); oA2 = mfma16(pfA, v, oA2); oB2 = mfma16(pfB, v, oB2);
          v = LD8(&vs[(48 + fr) * 64 + ko1]); oA3 = mfma16(pfA, v, oA3); oB3 = mfma16(pfB, v, oB3);
          __builtin_amdgcn_s_setprio(0);
        }
      }

      if (st2)                 asm volatile("s_waitcnt vmcnt(4)" ::: "memory");
      else if (t + 1 < nt)     asm volatile("s_waitcnt vmcnt(0)" ::: "memory");
      bar();
    }

    // epilogue: ls[r] is already the full row sum for row r4+r (no shuffles)
#define EPI_G(O0, O1, O2, O3, LSV, RB, r)                                      \
    {                                                                          \
      const float inv = 1.0f / LSV[r];                                         \
      const int qg = q0 + qw + RB + r4 + r;                                    \
      const size_t rowoff = ((size_t)bb * 2048 + qg) * 1024 + h * 64;          \
      obuf[rowoff + fr] = f2bf(O0[r] * inv);                                   \
      obuf[rowoff + 16 + fr] = f2bf(O1[r] * inv);                              \
      obuf[rowoff + 32 + fr] = f2bf(O2[r] * inv);                              \
      obuf[rowoff + 48 + fr] = f2bf(O3[r] * inv);                              \
    }
    EPI_G(oA0, oA1, oA2, oA3, lsA, 0, 0)
    EPI_G(oA0, oA1, oA2, oA3, lsA, 0, 1)
    EPI_G(oA0, oA1, oA2, oA3, lsA, 0, 2)
    EPI_G(oA0, oA1, oA2, oA3, lsA, 0, 3)
    EPI_G(oB0, oB1, oB2, oB3, lsB, 16, 0)
    EPI_G(oB0, oB1, oB2, oB3, lsB, 16, 1)
    EPI_G(oB0, oB1, oB2, oB3, lsB, 16, 2)
    EPI_G(oB0, oB1, oB2, oB3, lsB, 16, 3)
#undef EPI_G
  }
}

// ---------------- launch ----------------

extern "C" void kernel_launch(void* const* d_in, const int* in_sizes, int n_in,
                              void* d_out, int out_size, void* d_ws, size_t ws_size,
                              hipStream_t stream) {
  const float* x  = (const float*)d_in[0];
  const float* Wq = (const float*)d_in[1];
  const float* bq = (const float*)d_in[2];
  const float* Wk = (const float*)d_in[3];
  const float* bk = (const float*)d_in[4];
  const float* Wv = (const float*)d_in[5];
  const float* bv = (const float*)d_in[6];
  const float* Wp = (const float*)d_in[7];
  const float* bp = (const float*)d_in[8];

  char* ws = (char*)d_ws;
  size_t off = 0;
  auto alloc = [&](size_t bytes) -> void* {
    void* p = ws + off;
    off += (bytes + 255) & ~(size_t)255;
    return p;
  };
  u16*   xb     = (u16*)  alloc((size_t)8192 * 1024 * 2);  // reused as vT after QKV GEMM
  u16*   wqkv_t = (u16*)  alloc((size_t)3072 * 1024 * 2);
  float* biasq  = (float*)alloc((size_t)3072 * 4);
  u16*   wpt    = (u16*)  alloc((size_t)1024 * 1024 * 2);
  u16*   qkv    = (u16*)  alloc((size_t)8192 * 3072 * 2);
  u16*   obuf   = (u16*)  alloc((size_t)8192 * 1024 * 2);
  u16*   vT     = xb;  // xb is dead after the QKV GEMM; vT is exactly 16 MB too
  (void)ws_size; (void)in_sizes; (void)n_in; (void)out_size;

  cvt_x_kernel<<<2048, 256, 0, stream>>>(x, xb, 8192 * 1024 / 8);
  cvt_wqkv_kernel<<<dim3(16, 16, 3), 256, 0, stream>>>(Wq, Wk, Wv, bq, bk, bv, wqkv_t, biasq);
  cvt_wp_kernel<<<dim3(16, 16), 256, 0, stream>>>(Wp, wpt);
  gemm19_kernel<false><<<768, 256, 0, stream>>>(xb, wqkv_t, biasq, qkv, 8192, 3072, 1024, 12);
  transpose_v_kernel<<<dim3(32, 16, 4), 256, 0, stream>>>(qkv, vT);
  attn_kernel<<<512, 256, 0, stream>>>(qkv, vT, obuf);
  gemm9_kernel<true><<<256, 512, 0, stream>>>(obuf, wpt, bp, d_out, 8192, 1024, 1024, 4);
}

// Round 24
// 152.856 us; speedup vs baseline: 1.1367x; 1.1367x over previous
//
#include <hip/hip_runtime.h>
#include <hip/hip_bf16.h>
#include <stdint.h>

// B=4, T=2048, C=1024, H=16, hd=64
// qkv bf16 [8192][3072] (cols: 0..1023=Q, 1024..2047=K, 2048..3071=V; within: h*64+d)
//   NOTE: Wq/bq are pre-scaled by log2(e)/32, so softmax = exp2(S).
// vT bf16 [(bb*16+h)*64+d][2048]: sigma-permuted per 64-token tile.
// r24 = exact revert to r22 (measured best 152.99us): QKV gemm17, proj gemm9,
// attn r22 (MFMA row-sums, tri-buffer). gemm19 (A-direct) refuted in r23.

typedef unsigned short u16;
typedef __attribute__((ext_vector_type(4))) float f32x4;
typedef __attribute__((ext_vector_type(8))) __bf16 bf16x8;
typedef __attribute__((ext_vector_type(2))) __bf16 bf16x2;

#define DEV static __device__ __forceinline__

DEV u16 f2bf(float f) {  // RNE float->bf16 (finite inputs only)
  uint32_t u = __builtin_bit_cast(uint32_t, f);
  return (u16)((u + 0x7FFFu + ((u >> 16) & 1u)) >> 16);
}

DEV uint pack2(float a, float b) {  // v_cvt_pk_bf16_f32 via vector of casts
  bf16x2 v;
  v.x = (__bf16)a;
  v.y = (__bf16)b;
  return __builtin_bit_cast(uint, v);
}

#if __has_builtin(__builtin_amdgcn_exp2f)
DEV float fexp2(float x) { return __builtin_amdgcn_exp2f(x); }
#else
DEV float fexp2(float x) { return __expf(x * 0.69314718056f); }
#endif

DEV void gload_lds16(const void* g, void* lds) {  // 16B/lane global->LDS direct
  auto gp = reinterpret_cast<const __attribute__((address_space(1))) uint32_t*>(
      reinterpret_cast<uintptr_t>(g));
  auto lp = reinterpret_cast<__attribute__((address_space(3))) uint32_t*>(
      static_cast<uint32_t>(reinterpret_cast<uintptr_t>(lds)));
  __builtin_amdgcn_global_load_lds(gp, lp, 16, 0, 0);
}

DEV f32x4 mfma16(bf16x8 a, bf16x8 b, f32x4 c) {
  return __builtin_amdgcn_mfma_f32_16x16x32_bf16(a, b, c, 0, 0, 0);
}

DEV void bar() {  // raw s_barrier + compiler memory fence
  asm volatile("" ::: "memory");
  __builtin_amdgcn_s_barrier();
  asm volatile("" ::: "memory");
}

#define LD8(p) (*reinterpret_cast<const bf16x8*>(p))
#define LDU4(p) (*reinterpret_cast<const uint4*>(p))

// ---------------- conversion kernels ----------------

__global__ void cvt_x_kernel(const float* __restrict__ x, u16* __restrict__ xb, int n8) {
  int i = blockIdx.x * blockDim.x + threadIdx.x;
  int stride = gridDim.x * blockDim.x;
  for (; i < n8; i += stride) {
    const float4* xp = reinterpret_cast<const float4*>(x) + 2 * (size_t)i;
    float4 a = xp[0], b = xp[1];
    uint4 o;
    o.x = pack2(a.x, a.y);
    o.y = pack2(a.z, a.w);
    o.z = pack2(b.x, b.y);
    o.w = pack2(b.z, b.w);
    reinterpret_cast<uint4*>(xb)[i] = o;
  }
}

// Wq/Wk/Wv [16][1024][64] -> wt[n=which*1024+h*64+d][c] (bf16), biasq[n].
__global__ void cvt_wqkv_kernel(const float* __restrict__ Wq, const float* __restrict__ Wk,
                                const float* __restrict__ Wv, const float* __restrict__ bq,
                                const float* __restrict__ bk, const float* __restrict__ bv,
                                u16* __restrict__ wt, float* __restrict__ biasq) {
  __shared__ u16 tle[64 * 72];
  const int tid = threadIdx.x;
  const int ct = blockIdx.x;     // c-tile 0..15
  const int h = blockIdx.y;      // 0..15
  const int which = blockIdx.z;  // 0..2
  const float* W = (which == 0) ? Wq : (which == 1) ? Wk : Wv;
  const float* Bb = (which == 0) ? bq : (which == 1) ? bk : bv;
  const float scl = (which == 0) ? 0.045084220027780106f : 1.0f;  // log2(e)/32
#pragma unroll
  for (int i = 0; i < 4; ++i) {
    int idx = i * 256 + tid;
    int c_l = idx >> 4, d4 = (idx & 15) * 4;
    float4 v = *reinterpret_cast<const float4*>(&W[((size_t)(h * 1024 + ct * 64 + c_l)) * 64 + d4]);
    tle[(d4 + 0) * 72 + c_l] = f2bf(v.x * scl);
    tle[(d4 + 1) * 72 + c_l] = f2bf(v.y * scl);
    tle[(d4 + 2) * 72 + c_l] = f2bf(v.z * scl);
    tle[(d4 + 3) * 72 + c_l] = f2bf(v.w * scl);
  }
  __syncthreads();
#pragma unroll
  for (int i = 0; i < 2; ++i) {
    int idx = i * 256 + tid;
    int d_o = idx >> 3, c8 = (idx & 7) * 8;
    uint4 v = LDU4(&tle[d_o * 72 + c8]);
    *reinterpret_cast<uint4*>(&wt[(size_t)(which * 1024 + h * 64 + d_o) * 1024 + ct * 64 + c8]) = v;
  }
  if (ct == 0 && tid < 64) biasq[which * 1024 + h * 64 + tid] = Bb[h * 64 + tid] * scl;
}

// Wp [1024][1024] -> wpt[n][c] = Wp[c][n]
__global__ void cvt_wp_kernel(const float* __restrict__ Wp, u16* __restrict__ wpt) {
  __shared__ u16 tle[64 * 72];
  const int tid = threadIdx.x;
  const int ct = blockIdx.x;
  const int nt = blockIdx.y;
#pragma unroll
  for (int i = 0; i < 4; ++i) {
    int idx = i * 256 + tid;
    int c_l = idx >> 4, n4 = (idx & 15) * 4;
    float4 v = *reinterpret_cast<const float4*>(&Wp[(size_t)(ct * 64 + c_l) * 1024 + nt * 64 + n4]);
    tle[(n4 + 0) * 72 + c_l] = f2bf(v.x);
    tle[(n4 + 1) * 72 + c_l] = f2bf(v.y);
    tle[(n4 + 2) * 72 + c_l] = f2bf(v.z);
    tle[(n4 + 3) * 72 + c_l] = f2bf(v.w);
  }
  __syncthreads();
#pragma unroll
  for (int i = 0; i < 2; ++i) {
    int idx = i * 256 + tid;
    int n_o = idx >> 3, c8 = (idx & 7) * 8;
    uint4 v = LDU4(&tle[n_o * 72 + c8]);
    *reinterpret_cast<uint4*>(&wpt[(size_t)(nt * 64 + n_o) * 1024 + ct * 64 + c8]) = v;
  }
}

// qkv V-part -> vT[(bb*16+h)*64+d][2048], sigma-permuted per 64-token tile.
__global__ __launch_bounds__(256)
void transpose_v_kernel(const u16* __restrict__ qkv, u16* __restrict__ vT) {
  __shared__ alignas(16) u16 tle[64 * 72];
  const int tid = threadIdx.x;
  const int tt = blockIdx.x;  // token tile 0..31
  const int h = blockIdx.y;   // 0..15
  const int bb = blockIdx.z;  // 0..3
  const size_t rbase = ((size_t)bb * 2048 + tt * 64) * 3072 + 2048 + h * 64;
#pragma unroll
  for (int i = 0; i < 2; ++i) {
    int idx = i * 256 + tid;  // 0..511
    int s = idx >> 3, c8 = (idx & 7) * 8;
    *reinterpret_cast<uint4*>(&tle[s * 72 + c8]) = LDU4(&qkv[rbase + (size_t)s * 3072 + c8]);
  }
  __syncthreads();
#pragma unroll
  for (int i = 0; i < 2; ++i) {
    int idx = i * 256 + tid;
    int d = idx >> 3, cb = idx & 7;
    uint4 o;
    o.x = (uint)tle[(2 * cb + 0) * 72 + d] | ((uint)tle[(16 + 2 * cb + 0) * 72 + d] << 16);
    o.y = (uint)tle[(32 + 2 * cb + 0) * 72 + d] | ((uint)tle[(48 + 2 * cb + 0) * 72 + d] << 16);
    o.z = (uint)tle[(2 * cb + 1) * 72 + d] | ((uint)tle[(16 + 2 * cb + 1) * 72 + d] << 16);
    o.w = (uint)tle[(32 + 2 * cb + 1) * 72 + d] | ((uint)tle[(48 + 2 * cb + 1) * 72 + d] << 16);
    *reinterpret_cast<uint4*>(
        &vT[((size_t)(bb * 16 + h) * 64 + d) * 2048 + tt * 64 + cb * 8]) = o;
  }
}

// ---------------- gemm17: 128x256, BK=32, 48KB, 4 waves x (64x128) — for QKV ----------------

template <bool OUT_F32>
__global__ __launch_bounds__(256, 3)
void gemm17_kernel(const u16* __restrict__ A, const u16* __restrict__ Bt,
                   const float* __restrict__ bias, void* __restrict__ Cout,
                   int M, int N, int K, int nbn) {
  __shared__ alignas(16) u16 LA[2 * 4096];  // 2 x (128x32) = 16 KB
  __shared__ alignas(16) u16 LB[2 * 8192];  // 2 x (256x32) = 32 KB

  const int tid = threadIdx.x;   // 0..255
  const int lane = tid & 63;
  const int wave = tid >> 6;     // 0..3
  const int wm = wave >> 1;      // 0..1 -> rows wm*64
  const int wn = wave & 1;       // 0..1 -> cols wn*128
  const int fr = lane & 15;
  const int kg = lane >> 4;
  const int r4 = kg * 4;

  const int nwg = gridDim.x;
  const int swz = (blockIdx.x & 7) * (nwg >> 3) + (blockIdx.x >> 3);
  const int m0 = (swz / nbn) * 128;
  const int n0 = (swz % nbn) * 256;
  const int NT = K >> 5;

  auto stageA = [&](int kt, u16* d) {
#pragma unroll
    for (int i = 0; i < 2; ++i) {
      const int c = i * 256 + tid;
      const int row = c >> 2;
      const int ss = (((c & 3) ^ ((row >> 1) & 3)) << 3);
      gload_lds16(A + (size_t)(m0 + row) * K + (size_t)kt * 32 + ss, d + c * 8);
    }
  };
  auto stageB = [&](int kt, u16* d) {
#pragma unroll
    for (int i = 0; i < 4; ++i) {
      const int c = i * 256 + tid;
      const int row = c >> 2;
      const int ss = (((c & 3) ^ ((row >> 1) & 3)) << 3);
      gload_lds16(Bt + (size_t)(n0 + row) * K + (size_t)kt * 32 + ss, d + c * 8);
    }
  };

  f32x4 acc[4][8] = {};

  stageA(0, LA);
  stageB(0, LB);
  asm volatile("s_waitcnt vmcnt(0)" ::: "memory");
  bar();

  for (int kt = 0; kt < NT; ++kt) {
    const bool st1 = (kt + 1 < NT);
    u16* la = LA + (kt & 1) * 4096;
    u16* lb = LB + (kt & 1) * 8192;

    if (st1) {
      stageA(kt + 1, LA + ((kt + 1) & 1) * 4096);
      stageB(kt + 1, LB + ((kt + 1) & 1) * 8192);
    }

    bf16x8 aF[4];
#pragma unroll
    for (int m = 0; m < 4; ++m) {
      const int R = wm * 64 + m * 16 + fr;
      aF[m] = LD8(&la[R * 32 + ((kg ^ ((R >> 1) & 3)) << 3)]);
    }

    __builtin_amdgcn_s_setprio(1);
#pragma unroll
    for (int n = 0; n < 8; ++n) {
      const int R = wn * 128 + n * 16 + fr;
      bf16x8 bF = LD8(&lb[R * 32 + ((kg ^ ((R >> 1) & 3)) << 3)]);
#pragma unroll
      for (int m = 0; m < 4; ++m)
        acc[m][n] = mfma16(aF[m], bF, acc[m][n]);
    }
    __builtin_amdgcn_s_setprio(0);

    if (st1) {
      asm volatile("s_waitcnt vmcnt(0)" ::: "memory");
      bar();
    }
  }

#pragma unroll
  for (int m = 0; m < 4; ++m) {
    const int row = m0 + wm * 64 + m * 16 + r4;
#pragma unroll
    for (int n = 0; n < 8; ++n) {
      const int col = n0 + wn * 128 + n * 16 + fr;
      const float bv = bias[col];
#pragma unroll
      for (int r = 0; r < 4; ++r) {
        float v = acc[m][n][r] + bv;
        size_t off = (size_t)(row + r) * N + col;
        if constexpr (OUT_F32) reinterpret_cast<float*>(Cout)[off] = v;
        else                   reinterpret_cast<u16*>(Cout)[off] = f2bf(v);
      }
    }
  }
}

// ---------------- gemm9: 128x256, BK=64, A-dbuf + B-tribuf (counted vmcnt) — for proj ----------------

template <bool OUT_F32>
__global__ __launch_bounds__(512, 2)
void gemm9_kernel(const u16* __restrict__ A, const u16* __restrict__ Bt,
                  const float* __restrict__ bias, void* __restrict__ Cout,
                  int M, int N, int K, int nbn) {
  __shared__ alignas(16) u16 LA[2 * 8192];
  __shared__ alignas(16) u16 LB[3 * 16384];

  const int tid = threadIdx.x;
  const int lane = tid & 63;
  const int wave = tid >> 6;
  const int wm = wave >> 2;
  const int wn = wave & 3;
  const int fr = lane & 15;
  const int kg = lane >> 4;
  const int f7 = fr & 7;
  const int r4 = kg * 4;

  const int nwg = gridDim.x;
  const int swz = (blockIdx.x & 7) * (nwg >> 3) + (blockIdx.x >> 3);
  const int m0 = (swz / nbn) * 128;
  const int n0 = (swz % nbn) * 256;
  const int NT = K >> 6;

  const int srow = tid >> 3;
  const int sgcol = ((tid & 7) ^ (srow & 7)) << 3;
  const size_t aOff = (size_t)(m0 + srow) * K + sgcol;
  const size_t bOff = (size_t)(n0 + srow) * K + sgcol;
  const int ldst = tid * 8;

  auto stageA = [&](int kt, u16* labuf) {
    gload_lds16(A + aOff + (size_t)kt * 64, labuf + ldst);
    gload_lds16(A + aOff + (size_t)64 * K + (size_t)kt * 64, labuf + 4096 + ldst);
  };
  auto stageB = [&](int kt, u16* lbbuf) {
    gload_lds16(Bt + bOff + (size_t)kt * 64, lbbuf + ldst);
    gload_lds16(Bt + bOff + (size_t)64 * K + (size_t)kt * 64, lbbuf + 4096 + ldst);
    gload_lds16(Bt + bOff + (size_t)128 * K + (size_t)kt * 64, lbbuf + 8192 + ldst);
    gload_lds16(Bt + bOff + (size_t)192 * K + (size_t)kt * 64, lbbuf + 12288 + ldst);
  };

  f32x4 acc[4][4] = {};

  stageA(0, LA);
  stageB(0, LB);
  if (NT > 1) {
    stageB(1, LB + 16384);
    asm volatile("s_waitcnt vmcnt(4)" ::: "memory");
  } else {
    asm volatile("s_waitcnt vmcnt(0)" ::: "memory");
  }
  bar();

  for (int kt = 0; kt < NT; ++kt) {
    const bool st1 = (kt + 1 < NT);
    const bool st2 = (kt + 2 < NT);
    u16* laCur = LA + (kt & 1) * 8192;
    u16* lbCur = LB + (kt % 3) * 16384;

    if (st1) stageA(kt + 1, LA + ((kt + 1) & 1) * 8192);
    if (st2) stageB(kt + 2, LB + ((kt + 2) % 3) * 16384);

    bf16x8 aF[4][2], bF[4][2];
#pragma unroll
    for (int m = 0; m < 4; ++m)
#pragma unroll
      for (int ks = 0; ks < 2; ++ks)
        aF[m][ks] = LD8(&laCur[wm * 4096 + (m * 16 + fr) * 64 + (((ks * 4 + kg) ^ f7) << 3)]);
#pragma unroll
    for (int n = 0; n < 4; ++n)
#pragma unroll
      for (int ks = 0; ks < 2; ++ks)
        bF[n][ks] = LD8(&lbCur[wn * 4096 + (n * 16 + fr) * 64 + (((ks * 4 + kg) ^ f7) << 3)]);

    __builtin_amdgcn_s_setprio(1);
#pragma unroll
    for (int ks = 0; ks < 2; ++ks)
#pragma unroll
      for (int m = 0; m < 4; ++m)
#pragma unroll
        for (int n = 0; n < 4; ++n)
          acc[m][n] = mfma16(aF[m][ks], bF[n][ks], acc[m][n]);
    __builtin_amdgcn_s_setprio(0);

    if (st1) {
      if (st2) asm volatile("s_waitcnt vmcnt(4)" ::: "memory");
      else     asm volatile("s_waitcnt vmcnt(0)" ::: "memory");
      bar();
    }
  }

#pragma unroll
  for (int m = 0; m < 4; ++m) {
    const int row = m0 + wm * 64 + m * 16 + r4;
#pragma unroll
    for (int n = 0; n < 4; ++n) {
      const int col = n0 + wn * 64 + n * 16 + fr;
      const float bv = bias[col];
#pragma unroll
      for (int r = 0; r < 4; ++r) {
        float v = acc[m][n][r] + bv;
        size_t off = (size_t)(row + r) * N + col;
        if constexpr (OUT_F32) reinterpret_cast<float*>(Cout)[off] = v;
        else                   reinterpret_cast<u16*>(Cout)[off] = f2bf(v);
      }
    }
  }
}

// ---------------- causal flash attention: 4 waves x 32 q-rows, MFMA row-sums ----------

__global__ __launch_bounds__(256, 2)
void attn_kernel(const u16* __restrict__ qkv, const u16* __restrict__ vT,
                 u16* __restrict__ obuf) {
  __shared__ alignas(16) u16 Ks[3][64 * 64];
  __shared__ alignas(16) u16 Vs[3][64 * 64];
  __shared__ alignas(16) u16 Ps[4][32 * 72];

  const int tid = threadIdx.x;
  const int lane = tid & 63;
  const int wave = tid >> 6;  // 0..3

  const int gid = blockIdx.x;
  const int xcd = gid & 7;
  const int j = gid >> 3;            // 0..63
  const int g = xcd * 8 + (j >> 3);  // 0..63 (b,h) group
  const int pair = j & 7;            // 0..7
  const int bb = g >> 4;
  const int h = g & 15;

  const size_t baseQ = (size_t)bb * 2048 * 3072 + h * 64;
  const size_t baseK = baseQ + 1024;
  const size_t baseVt = (size_t)(bb * 16 + h) * 64 * 2048;

  const int fr = lane & 15;
  const int kg = lane >> 4;
  const int kg8 = kg * 8;
  const int r4 = kg * 4;
  const int f7 = fr & 7;
  const int ko0 = (kg ^ f7) * 8;        // ks=0 swizzled u16 offset
  const int ko1 = ((4 + kg) ^ f7) * 8;  // ks=1
  u16* __restrict__ Pw = &Ps[wave][0];

  const __bf16 one1 = (__bf16)1.0f;
  const bf16x8 one8 = {one1, one1, one1, one1, one1, one1, one1, one1};

  auto stageKV = [&](int t, int bi) {  // 4 gloads/thread (full 64x64 K and V tiles)
    const u16* kS = qkv + baseK + (size_t)t * 64 * 3072;
    const u16* vS = vT + baseVt + (size_t)t * 64;
#pragma unroll
    for (int i = 0; i < 2; ++i) {
      const int c = i * 256 + tid;
      const int rr = c >> 3;
      const int ss = ((c & 7) ^ (rr & 7)) * 8;
      gload_lds16(kS + (size_t)rr * 3072 + ss, &Ks[bi][c * 8]);
      gload_lds16(vS + (size_t)rr * 2048 + ss, &Vs[bi][c * 8]);
    }
  };

  for (int half = 0; half < 2; ++half) {
    const int qt = half ? (15 - pair) : pair;
    const int q0 = qt * 128;
    const int nt = 2 * qt + 2;              // >= 2 always
    const int qw = wave * 32;
    const int myNt = nt - 1 + (wave >> 1);  // waves 0,1 skip final tile (fully masked)
    const int qdb = qw & 63;                // diag threshold base (0 or 32)

    const u16* qr = &qkv[baseQ + (size_t)(q0 + qw + fr) * 3072 + kg8];
    bf16x8 aq00 = LD8(qr), aq01 = LD8(qr + 32);
    bf16x8 aq10 = LD8(qr + 16 * 3072), aq11 = LD8(qr + 16 * 3072 + 32);

    f32x4 lsA = {}, lsB = {};
    f32x4 oA0 = {}, oA1 = {}, oA2 = {}, oA3 = {};
    f32x4 oB0 = {}, oB1 = {}, oB2 = {}, oB3 = {};

    // prologue: stage tiles 0,1; drain only tile 0 (counted)
    stageKV(0, 0);
    stageKV(1, 1);
    asm volatile("s_waitcnt vmcnt(4)" ::: "memory");
    bar();

    for (int t = 0; t < nt; ++t) {
      const bool st2 = (t + 2 < nt);
      if (st2) stageKV(t + 2, (t + 2) % 3);

      if (t < myNt) {
        const u16* ks = &Ks[t % 3][0];
        const u16* vs = &Vs[t % 3][0];

        f32x4 sA0 = {}, sA1 = {}, sA2 = {}, sA3 = {};
        f32x4 sB0 = {}, sB1 = {}, sB2 = {}, sB3 = {};
        {
          bf16x8 b;
          __builtin_amdgcn_s_setprio(1);
          b = LD8(&ks[(fr) * 64 + ko0]);      sA0 = mfma16(aq00, b, sA0); sB0 = mfma16(aq10, b, sB0);
          b = LD8(&ks[(16 + fr) * 64 + ko0]); sA1 = mfma16(aq00, b, sA1); sB1 = mfma16(aq10, b, sB1);
          b = LD8(&ks[(32 + fr) * 64 + ko0]); sA2 = mfma16(aq00, b, sA2); sB2 = mfma16(aq10, b, sB2);
          b = LD8(&ks[(48 + fr) * 64 + ko0]); sA3 = mfma16(aq00, b, sA3); sB3 = mfma16(aq10, b, sB3);
          b = LD8(&ks[(fr) * 64 + ko1]);      sA0 = mfma16(aq01, b, sA0); sB0 = mfma16(aq11, b, sB0);
          b = LD8(&ks[(16 + fr) * 64 + ko1]); sA1 = mfma16(aq01, b, sA1); sB1 = mfma16(aq11, b, sB1);
          b = LD8(&ks[(32 + fr) * 64 + ko1]); sA2 = mfma16(aq01, b, sA2); sB2 = mfma16(aq11, b, sB2);
          b = LD8(&ks[(48 + fr) * 64 + ko1]); sA3 = mfma16(aq01, b, sA3); sB3 = mfma16(aq11, b, sB3);
          __builtin_amdgcn_s_setprio(0);
        }

        const bool diag = (t == myNt - 1);
#define SM_ROW_G(S0, S1, S2, S3, RB, r)                                        \
        {                                                                      \
          const int qd = qdb + RB + r4 + r;                                    \
          float p0 = fexp2(S0[r]);                                             \
          float p1 = fexp2(S1[r]);                                             \
          float p2 = fexp2(S2[r]);                                             \
          float p3 = fexp2(S3[r]);                                             \
          if (diag) {                                                          \
            if (fr > qd) p0 = 0.f;                                             \
            if (fr + 16 > qd) p1 = 0.f;                                        \
            if (fr + 32 > qd) p2 = 0.f;                                        \
            if (fr + 48 > qd) p3 = 0.f;                                        \
          }                                                                    \
          uint2 w;                                                             \
          w.x = pack2(p0, p1);                                                 \
          w.y = pack2(p2, p3);                                                 \
          *reinterpret_cast<uint2*>(&Pw[(RB + r4 + r) * 72 + fr * 4]) = w;     \
        }
        SM_ROW_G(sA0, sA1, sA2, sA3, 0, 0)
        SM_ROW_G(sA0, sA1, sA2, sA3, 0, 1)
        SM_ROW_G(sA0, sA1, sA2, sA3, 0, 2)
        SM_ROW_G(sA0, sA1, sA2, sA3, 0, 3)
        SM_ROW_G(sB0, sB1, sB2, sB3, 16, 0)
        SM_ROW_G(sB0, sB1, sB2, sB3, 16, 1)
        SM_ROW_G(sB0, sB1, sB2, sB3, 16, 2)
        SM_ROW_G(sB0, sB1, sB2, sB3, 16, 3)
#undef SM_ROW_G

        {
          bf16x8 pfA = LD8(&Pw[fr * 72 + kg8]);
          bf16x8 pfB = LD8(&Pw[(16 + fr) * 72 + kg8]);
          bf16x8 v;
          __builtin_amdgcn_s_setprio(1);
          lsA = mfma16(pfA, one8, lsA);       // row sums (all D cols equal)
          lsB = mfma16(pfB, one8, lsB);
          v = LD8(&vs[(fr) * 64 + ko0]);      oA0 = mfma16(pfA, v, oA0); oB0 = mfma16(pfB, v, oB0);
          v = LD8(&vs[(16 + fr) * 64 + ko0]); oA1 = mfma16(pfA, v, oA1); oB1 = mfma16(pfB, v, oB1);
          v = LD8(&vs[(32 + fr) * 64 + ko0]); oA2 = mfma16(pfA, v, oA2); oB2 = mfma16(pfB, v, oB2);
          v = LD8(&vs[(48 + fr) * 64 + ko0]); oA3 = mfma16(pfA, v, oA3); oB3 = mfma16(pfB, v, oB3);
          pfA = LD8(&Pw[fr * 72 + 32 + kg8]);
          pfB = LD8(&Pw[(16 + fr) * 72 + 32 + kg8]);
          lsA = mfma16(pfA, one8, lsA);
          lsB = mfma16(pfB, one8, lsB);
          v = LD8(&vs[(fr) * 64 + ko1]);      oA0 = mfma16(pfA, v, oA0); oB0 = mfma16(pfB, v, oB0);
          v = LD8(&vs[(16 + fr) * 64 + ko1]); oA1 = mfma16(pfA, v, oA1); oB1 = mfma16(pfB, v, oB1);
          v = LD8(&vs[(32 + fr) * 64 + ko1]); oA2 = mfma16(pfA, v, oA2); oB2 = mfma16(pfB, v, oB2);
          v = LD8(&vs[(48 + fr) * 64 + ko1]); oA3 = mfma16(pfA, v, oA3); oB3 = mfma16(pfB, v, oB3);
          __builtin_amdgcn_s_setprio(0);
        }
      }

      if (st2)                 asm volatile("s_waitcnt vmcnt(4)" ::: "memory");
      else if (t + 1 < nt)     asm volatile("s_waitcnt vmcnt(0)" ::: "memory");
      bar();
    }

    // epilogue: ls[r] is already the full row sum for row r4+r (no shuffles)
#define EPI_G(O0, O1, O2, O3, LSV, RB, r)                                      \
    {                                                                          \
      const float inv = 1.0f / LSV[r];                                         \
      const int qg = q0 + qw + RB + r4 + r;                                    \
      const size_t rowoff = ((size_t)bb * 2048 + qg) * 1024 + h * 64;          \
      obuf[rowoff + fr] = f2bf(O0[r] * inv);                                   \
      obuf[rowoff + 16 + fr] = f2bf(O1[r] * inv);                              \
      obuf[rowoff + 32 + fr] = f2bf(O2[r] * inv);                              \
      obuf[rowoff + 48 + fr] = f2bf(O3[r] * inv);                              \
    }
    EPI_G(oA0, oA1, oA2, oA3, lsA, 0, 0)
    EPI_G(oA0, oA1, oA2, oA3, lsA, 0, 1)
    EPI_G(oA0, oA1, oA2, oA3, lsA, 0, 2)
    EPI_G(oA0, oA1, oA2, oA3, lsA, 0, 3)
    EPI_G(oB0, oB1, oB2, oB3, lsB, 16, 0)
    EPI_G(oB0, oB1, oB2, oB3, lsB, 16, 1)
    EPI_G(oB0, oB1, oB2, oB3, lsB, 16, 2)
    EPI_G(oB0, oB1, oB2, oB3, lsB, 16, 3)
#undef EPI_G
  }
}

// ---------------- launch ----------------

extern "C" void kernel_launch(void* const* d_in, const int* in_sizes, int n_in,
                              void* d_out, int out_size, void* d_ws, size_t ws_size,
                              hipStream_t stream) {
  const float* x  = (const float*)d_in[0];
  const float* Wq = (const float*)d_in[1];
  const float* bq = (const float*)d_in[2];
  const float* Wk = (const float*)d_in[3];
  const float* bk = (const float*)d_in[4];
  const float* Wv = (const float*)d_in[5];
  const float* bv = (const float*)d_in[6];
  const float* Wp = (const float*)d_in[7];
  const float* bp = (const float*)d_in[8];

  char* ws = (char*)d_ws;
  size_t off = 0;
  auto alloc = [&](size_t bytes) -> void* {
    void* p = ws + off;
    off += (bytes + 255) & ~(size_t)255;
    return p;
  };
  u16*   xb     = (u16*)  alloc((size_t)8192 * 1024 * 2);  // reused as vT after QKV GEMM
  u16*   wqkv_t = (u16*)  alloc((size_t)3072 * 1024 * 2);
  float* biasq  = (float*)alloc((size_t)3072 * 4);
  u16*   wpt    = (u16*)  alloc((size_t)1024 * 1024 * 2);
  u16*   qkv    = (u16*)  alloc((size_t)8192 * 3072 * 2);
  u16*   obuf   = (u16*)  alloc((size_t)8192 * 1024 * 2);
  u16*   vT     = xb;  // xb is dead after the QKV GEMM; vT is exactly 16 MB too
  (void)ws_size; (void)in_sizes; (void)n_in; (void)out_size;

  cvt_x_kernel<<<2048, 256, 0, stream>>>(x, xb, 8192 * 1024 / 8);
  cvt_wqkv_kernel<<<dim3(16, 16, 3), 256, 0, stream>>>(Wq, Wk, Wv, bq, bk, bv, wqkv_t, biasq);
  cvt_wp_kernel<<<dim3(16, 16), 256, 0, stream>>>(Wp, wpt);
  gemm17_kernel<false><<<768, 256, 0, stream>>>(xb, wqkv_t, biasq, qkv, 8192, 3072, 1024, 12);
  transpose_v_kernel<<<dim3(32, 16, 4), 256, 0, stream>>>(qkv, vT);
  attn_kernel<<<512, 256, 0, stream>>>(qkv, vT, obuf);
  gemm9_kernel<true><<<256, 512, 0, stream>>>(obuf, wpt, bp, d_out, 8192, 1024, 1024, 4);
}